// Round 1
// baseline (160.073 us; speedup 1.0000x reference)
//
#include <hip/hip_runtime.h>
#include <math.h>

#define BDIM 4096
#define FIN  64
#define NK   512
#define FOUT 256

#define BB   16          // batch rows per block
#define KC   16          // k-chunk for weight staging
#define NCH  (NK / KC)   // 32 chunks
#define WPAD 4           // wt row pad (keeps 16B alignment, 2-way write conflict = free)

struct Smem {
    float rbf[BB][NK];       // 32 KB  unnormalized rbf values
    float invs[BB];          // 1/(1e-9 + rowsum)
    union {
        float xs[BB][FIN];           // phase 1: x tile (4 KB)
        float wt[KC][FOUT + WPAD];   // phase 2: transposed W chunk (16.6 KB)
    } u;
};

__global__ __launch_bounds__(256, 1) void rbf_fused_kernel(
    const float* __restrict__ x,     // [B][FIN]
    const float* __restrict__ w,     // [FOUT][NK]
    const float* __restrict__ cent,  // [NK][FIN]
    const float* __restrict__ ls,    // [NK]
    float* __restrict__ out)         // [B][FOUT]
{
    __shared__ Smem s;
    const int tid = threadIdx.x;
    const int b0  = blockIdx.x * BB;

    // ---- stage x tile: 1024 floats = 256 float4, coalesced ----
    {
        const float4* xg = (const float4*)(x + (size_t)b0 * FIN);
        ((float4*)&s.u.xs[0][0])[tid] = xg[tid];
    }
    __syncthreads();

    // ---- pull my row into registers ----
    const int r     = tid >> 4;   // 0..15
    const int kslot = tid & 15;   // 0..15
    float4 xr[16];
    #pragma unroll
    for (int j = 0; j < 16; ++j)
        xr[j] = ((const float4*)&s.u.xs[r][0])[j];
    __syncthreads();   // all xs reads done before wt overwrites the union

    // ---- distance + rbf phase: 32 k's per thread ----
    float psum = 0.f;
    for (int i = 0; i < NK / 16; ++i) {
        const int k = kslot + 16 * i;
        const float4* cg = (const float4*)(cent + (size_t)k * FIN);
        float s0 = 0.f, s1 = 0.f, s2 = 0.f, s3 = 0.f;
        #pragma unroll
        for (int j = 0; j < 16; ++j) {
            float4 c4 = cg[j];
            float4 xv = xr[j];
            float d0 = xv.x - c4.x;
            float d1 = xv.y - c4.y;
            float d2 = xv.z - c4.z;
            float d3 = xv.w - c4.w;
            s0 = fmaf(d0, d0, s0);
            s1 = fmaf(d1, d1, s1);
            s2 = fmaf(d2, d2, s2);
            s3 = fmaf(d3, d3, s3);
        }
        const float ssq = (s0 + s1) + (s2 + s3);
        const float e2  = __expf(2.f * ls[k]);   // exp(log_shapes)^2
        const float rb  = __expf(-(e2 * ssq));   // exp(-(eps*r)^2)
        s.rbf[r][k] = rb;
        psum += rb;
    }
    // 16-lane row reduction (threads of a row are contiguous lanes)
    #pragma unroll
    for (int m = 1; m < 16; m <<= 1)
        psum += __shfl_xor(psum, m, 16);
    if (kslot == 0)
        s.invs[r] = 1.f / (1e-9f + psum);

    // ---- GEMM phase: out[16][256] = rbf[16][512] * W[256][512]^T ----
    const int rowg = tid >> 6;   // 0..3  (4 rows each)
    const int colg = tid & 63;   // 0..63 (4 cols each)
    const int crow = tid >> 2;   // staging: rows crow + 64j
    const int kk4  = tid & 3;    // staging: k-quad within chunk

    float acc[4][4];
    #pragma unroll
    for (int a = 0; a < 4; ++a)
        #pragma unroll
        for (int b = 0; b < 4; ++b) acc[a][b] = 0.f;

    // preload chunk 0 into registers
    float4 stage[4];
    #pragma unroll
    for (int j = 0; j < 4; ++j)
        stage[j] = *(const float4*)(w + (size_t)(crow + 64 * j) * NK + 4 * kk4);

    for (int ch = 0; ch < NCH; ++ch) {
        __syncthreads();   // previous chunk's wt reads (or xs/rbf phase) done
        #pragma unroll
        for (int j = 0; j < 4; ++j) {
            const float4 v = stage[j];
            const int c = crow + 64 * j;
            s.u.wt[4 * kk4 + 0][c] = v.x;
            s.u.wt[4 * kk4 + 1][c] = v.y;
            s.u.wt[4 * kk4 + 2][c] = v.z;
            s.u.wt[4 * kk4 + 3][c] = v.w;
        }
        __syncthreads();   // wt visible

        // prefetch next chunk (in flight during compute)
        if (ch + 1 < NCH) {
            const int k0n = (ch + 1) * KC;
            #pragma unroll
            for (int j = 0; j < 4; ++j)
                stage[j] = *(const float4*)(w + (size_t)(crow + 64 * j) * NK + k0n + 4 * kk4);
        }

        const int k0 = ch * KC;
        #pragma unroll
        for (int kk = 0; kk < KC; kk += 4) {
            float pr[4][4];   // [jr][i]
            float wv[4][4];   // [i][jc]
            #pragma unroll
            for (int jr = 0; jr < 4; ++jr)
                *(float4*)&pr[jr][0] = *(const float4*)&s.rbf[rowg * 4 + jr][k0 + kk];
            #pragma unroll
            for (int i = 0; i < 4; ++i)
                *(float4*)&wv[i][0] = *(const float4*)&s.u.wt[kk + i][4 * colg];
            #pragma unroll
            for (int jr = 0; jr < 4; ++jr)
                #pragma unroll
                for (int i = 0; i < 4; ++i)
                    #pragma unroll
                    for (int jc = 0; jc < 4; ++jc)
                        acc[jr][jc] = fmaf(pr[jr][i], wv[i][jc], acc[jr][jc]);
        }
    }

    // ---- epilogue: scale by 1/(1e-9+sum) and store coalesced ----
    #pragma unroll
    for (int jr = 0; jr < 4; ++jr) {
        const int row = rowg * 4 + jr;
        const float iv = s.invs[row];
        float4 o;
        o.x = acc[jr][0] * iv;
        o.y = acc[jr][1] * iv;
        o.z = acc[jr][2] * iv;
        o.w = acc[jr][3] * iv;
        *(float4*)(out + (size_t)(b0 + row) * FOUT + 4 * colg) = o;
    }
}

extern "C" void kernel_launch(void* const* d_in, const int* in_sizes, int n_in,
                              void* d_out, int out_size, void* d_ws, size_t ws_size,
                              hipStream_t stream) {
    const float* x    = (const float*)d_in[0];   // [4096][64]
    const float* w    = (const float*)d_in[1];   // [256][512]
    const float* cent = (const float*)d_in[2];   // [512][64]
    const float* ls   = (const float*)d_in[3];   // [512]
    float* out        = (float*)d_out;           // [4096][256]

    dim3 grid(BDIM / BB);   // 256 blocks
    dim3 block(256);
    rbf_fused_kernel<<<grid, block, 0, stream>>>(x, w, cent, ls, out);
}